// Round 10
// baseline (65.456 us; speedup 1.0000x reference)
//
#include <hip/hip_runtime.h>
#include <hip/hip_bf16.h>

#define B 16
#define S 4096
#define D 256
#define U 256
#define ROWS 64
#define NCHK (S / ROWS)  // 64 chunks per batch

typedef short short8 __attribute__((ext_vector_type(8)));
typedef float f32x4 __attribute__((ext_vector_type(4)));

__device__ __forceinline__ ushort f2bf(float f) {
    union { float f; uint u; } x{f};
    uint r = (x.u + 0x7fffu + ((x.u >> 16) & 1u)) >> 16;  // RNE
    return (ushort)r;
}

__device__ __forceinline__ float fast_tanh(float x) {
    float e = __expf(2.0f * x);
    return 1.0f - 2.0f * __builtin_amdgcn_rcpf(e + 1.0f);
}

// KA: setup. blocks 0..15: pqb GEMV (ILP-parallel); blocks 16..23: W1 pack.
__global__ void ka_setup(const float* __restrict__ query, const float* __restrict__ W2,
                         const float* __restrict__ b2, const float* __restrict__ b1,
                         const float* __restrict__ W1, float* __restrict__ pqb,
                         ushort* __restrict__ W1p) {
    __shared__ float pp[4][U];
    int bid = blockIdx.x, t = threadIdx.x;
    if (bid < 16) {
        const float* qb = query + bid * D;
        int u0 = (t & 63) * 4, dc = t >> 6;
        float4 a = {0.f, 0.f, 0.f, 0.f};
#pragma unroll 16
        for (int i = 0; i < 64; ++i) {
            int d = dc * 64 + i;
            float qd = qb[d];
            float4 wv = *(const float4*)&W2[d * U + u0];
            a.x = fmaf(qd, wv.x, a.x);
            a.y = fmaf(qd, wv.y, a.y);
            a.z = fmaf(qd, wv.z, a.z);
            a.w = fmaf(qd, wv.w, a.w);
        }
        *(float4*)&pp[dc][u0] = a;
        __syncthreads();
        pqb[bid * U + t] = pp[0][t] + pp[1][t] + pp[2][t] + pp[3][t] + b2[t] + b1[t];
    } else {
        int kk = bid - 16;
        int l = t & 63, g = t >> 6;
        int colu0 = l & 15;
        int k0 = kk * 32 + (l >> 4) * 8;
#pragma unroll
        for (int i = 0; i < 4; ++i) {
            int nt = g * 4 + i;
            int colu = nt * 16 + colu0;
            ushort* dst = W1p + (((nt * 8) + kk) * 64 + l) * 8;
#pragma unroll
            for (int e = 0; e < 8; ++e) dst[e] = f2bf(W1[(k0 + e) * U + colu]);
        }
    }
}

// KB: per 64-row chunk. MFMA A-fragments loaded DIRECTLY from global (no staging
// phase, no pre-loop barrier) — loads and MFMA overlap across the 16 waves/CU.
// Wave 0 mirrors its converted fragments into swizzled LDS for the cpart pass.
__global__ __launch_bounds__(256, 4) void kb_scores(
    const float* __restrict__ values, const ushort* __restrict__ W1p,
    const float* __restrict__ pqb, const float* __restrict__ V,
    const float* __restrict__ bV, float* __restrict__ cstats,
    float* __restrict__ cpart, float* __restrict__ wout) {
    __shared__ ushort Alds[ROWS * 256];  // 32 KB, XOR-swizzled bf16 tile (wave 0 writes)
    __shared__ float red[4][ROWS];
    __shared__ float wch[ROWS];
    const int bid = blockIdx.x;
    const int t = threadIdx.x;
    const int w = t >> 6, l = t & 63;
    char* lds = (char*)Alds;
    const int b = bid >> 6;
    const int s0 = (bid & 63) * ROWS;
    const int lrow = l & 15, lk = l >> 4;

    const float* vbase = values + ((size_t)(b * S + s0)) * D;

    f32x4 acc[4][4];
#pragma unroll
    for (int mt = 0; mt < 4; ++mt)
#pragma unroll
        for (int nt = 0; nt < 4; ++nt) acc[mt][nt] = (f32x4){0.f, 0.f, 0.f, 0.f};

    for (int kk = 0; kk < 8; ++kk) {
        short8 bfr[4];
#pragma unroll
        for (int nt = 0; nt < 4; ++nt)
            bfr[nt] = *(const short8*)&W1p[((((w * 4 + nt) * 8) + kk) * 64 + l) * 8];
#pragma unroll
        for (int mt = 0; mt < 4; ++mt) {
            int row = mt * 16 + lrow;
            const float* p = vbase + row * 256 + kk * 32 + lk * 8;
            float4 a0 = *(const float4*)p;
            float4 a1 = *(const float4*)(p + 4);
            short8 af;
            af[0] = (short)f2bf(a0.x); af[1] = (short)f2bf(a0.y);
            af[2] = (short)f2bf(a0.z); af[3] = (short)f2bf(a0.w);
            af[4] = (short)f2bf(a1.x); af[5] = (short)f2bf(a1.y);
            af[6] = (short)f2bf(a1.z); af[7] = (short)f2bf(a1.w);
            if (w == 0) {
                int byte = (row * 512 + kk * 64 + lk * 16) ^ ((row & 7) << 4);
                *(short8*)(lds + byte) = af;
            }
#pragma unroll
            for (int nt = 0; nt < 4; ++nt)
                acc[mt][nt] = __builtin_amdgcn_mfma_f32_16x16x32_bf16(
                    af, bfr[nt], acc[mt][nt], 0, 0, 0);
        }
    }

    // epilogue: tanh, .V, reduce over u
    float bb[4], vv[4];
#pragma unroll
    for (int nt = 0; nt < 4; ++nt) {
        int u = (w * 4 + nt) * 16 + lrow;
        bb[nt] = pqb[b * U + u];
        vv[nt] = V[u];
    }
#pragma unroll
    for (int mt = 0; mt < 4; ++mt) {
#pragma unroll
        for (int r = 0; r < 4; ++r) {
            float s = 0.f;
#pragma unroll
            for (int nt = 0; nt < 4; ++nt)
                s += fast_tanh(acc[mt][nt][r] + bb[nt]) * vv[nt];
            s += __shfl_xor(s, 1);
            s += __shfl_xor(s, 2);
            s += __shfl_xor(s, 4);
            s += __shfl_xor(s, 8);
            if (lrow == 0) red[w][mt * 16 + lk * 4 + r] = s;
        }
    }
    __syncthreads();  // also publishes wave 0's Alds writes

    if (t < ROWS) {  // wave 0: chunk stats + unnormalized weights -> wout
        float s = red[0][t] + red[1][t] + red[2][t] + red[3][t] + bV[0];
        float m = s;
#pragma unroll
        for (int off = 32; off; off >>= 1) m = fmaxf(m, __shfl_xor(m, off));
        float z0 = __expf(s - m);
        wch[t] = z0;
        wout[b * S + s0 + t] = z0;  // KC rescales in place
        float z = z0;
#pragma unroll
        for (int off = 32; off; off >>= 1) z += __shfl_xor(z, off);
        if (t == 0) {
            cstats[2 * bid] = m;
            cstats[2 * bid + 1] = z;
        }
    }
    __syncthreads();

    // partial context from bf16 LDS: thread t owns column t (conflict-free u16 reads)
    union { uint i; float f; } cv;
    float cacc = 0.f;
#pragma unroll 8
    for (int r = 0; r < ROWS; ++r) {
        int byte = (r * 512 + t * 2) ^ ((r & 7) << 4);
        ushort u = *(const ushort*)(lds + byte);
        cv.i = (uint)u << 16;
        cacc = fmaf(wch[r], cv.f, cacc);
    }
    cpart[(size_t)bid * D + t] = cacc;
}

// KC: finisher, block = (batch b, quarter q).
__global__ void kc_final(const float* __restrict__ cstats, const float* __restrict__ cpart,
                         float* __restrict__ wout, float* __restrict__ ctx) {
    __shared__ float scl[NCHK];
    __shared__ float stats2[2];
    __shared__ float part[4][64];
    int b = blockIdx.x >> 2, q = blockIdx.x & 3;
    int t = threadIdx.x;

    if (t < NCHK) {
        float m = cstats[2 * (b * NCHK + t)];
        float z = cstats[2 * (b * NCHK + t) + 1];
        float M = m;
#pragma unroll
        for (int off = 32; off; off >>= 1) M = fmaxf(M, __shfl_xor(M, off));
        float zz = z * __expf(m - M);
#pragma unroll
        for (int off = 32; off; off >>= 1) zz += __shfl_xor(zz, off);
        scl[t] = __expf(m - M);
        if (t == 0) { stats2[0] = M; stats2[1] = zz; }
    }
    __syncthreads();
    float invZ = 1.0f / stats2[1];

    int tq = t >> 6, dl = t & 63;
    int d = q * 64 + dl;
    float acc = 0.f;
#pragma unroll
    for (int i = 0; i < 16; ++i) {
        int c = tq * 16 + i;
        acc = fmaf(scl[c], cpart[(size_t)(b * NCHK + c) * D + d], acc);
    }
    part[tq][dl] = acc;

#pragma unroll
    for (int i = 0; i < 4; ++i) {
        int ss = q * 1024 + i * 256 + t;
        wout[b * S + ss] *= scl[ss >> 6] * invZ;
    }
    __syncthreads();
    if (t < 64)
        ctx[b * D + q * 64 + t] =
            (part[0][t] + part[1][t] + part[2][t] + part[3][t]) * invZ;
}

extern "C" void kernel_launch(void* const* d_in, const int* in_sizes, int n_in,
                              void* d_out, int out_size, void* d_ws, size_t ws_size,
                              hipStream_t stream) {
    const float* values = (const float*)d_in[0];
    const float* query  = (const float*)d_in[1];
    const float* W1     = (const float*)d_in[2];
    const float* b1     = (const float*)d_in[3];
    const float* W2     = (const float*)d_in[4];
    const float* b2     = (const float*)d_in[5];
    const float* V      = (const float*)d_in[6];
    const float* bV     = (const float*)d_in[7];

    float* out  = (float*)d_out;
    float* ctx  = out;          // [B, D]
    float* wout = out + B * D;  // [B, S, 1]

    float* ws     = (float*)d_ws;
    float* pqb    = ws;                 // 4096
    float* cstats = pqb + B * U;        // 2048
    float* cpart  = cstats + 2048;      // B*NCHK*D = 262144
    ushort* W1p   = (ushort*)(cpart + (size_t)B * NCHK * D);  // 65536 ushorts

    ka_setup<<<24, 256, 0, stream>>>(query, W2, b2, b1, W1, pqb, W1p);
    kb_scores<<<B * NCHK, 256, 0, stream>>>(values, W1p, pqb, V, bV,
                                            cstats, cpart, wout);
    kc_final<<<B * 4, 256, 0, stream>>>(cstats, cpart, wout, ctx);
}

// Round 11
// 48.845 us; speedup vs baseline: 1.3401x; 1.3401x over previous
//
#include <hip/hip_runtime.h>
#include <hip/hip_bf16.h>

#define B 16
#define S 4096
#define D 256
#define U 256
#define ROWS 32
#define NCHK (S / ROWS)  // 128 chunks per batch

typedef short short8 __attribute__((ext_vector_type(8)));
typedef float f32x4 __attribute__((ext_vector_type(4)));

__device__ __forceinline__ ushort f2bf(float f) {
    union { float f; uint u; } x{f};
    uint r = (x.u + 0x7fffu + ((x.u >> 16) & 1u)) >> 16;  // RNE
    return (ushort)r;
}

__device__ __forceinline__ float fast_tanh(float x) {
    float e = __expf(2.0f * x);
    return 1.0f - 2.0f * __builtin_amdgcn_rcpf(e + 1.0f);
}

// KA: setup. blocks 0..15: pqb GEMV (ILP-parallel); blocks 16..23: W1 pack.
__global__ void ka_setup(const float* __restrict__ query, const float* __restrict__ W2,
                         const float* __restrict__ b2, const float* __restrict__ b1,
                         const float* __restrict__ W1, float* __restrict__ pqb,
                         ushort* __restrict__ W1p) {
    __shared__ float pp[4][U];
    int bid = blockIdx.x, t = threadIdx.x;
    if (bid < 16) {
        const float* qb = query + bid * D;
        int u0 = (t & 63) * 4, dc = t >> 6;
        float4 a = {0.f, 0.f, 0.f, 0.f};
#pragma unroll 16
        for (int i = 0; i < 64; ++i) {
            int d = dc * 64 + i;
            float qd = qb[d];
            float4 wv = *(const float4*)&W2[d * U + u0];
            a.x = fmaf(qd, wv.x, a.x);
            a.y = fmaf(qd, wv.y, a.y);
            a.z = fmaf(qd, wv.z, a.z);
            a.w = fmaf(qd, wv.w, a.w);
        }
        *(float4*)&pp[dc][u0] = a;
        __syncthreads();
        pqb[bid * U + t] = pp[0][t] + pp[1][t] + pp[2][t] + pp[3][t] + b2[t] + b1[t];
    } else {
        int kk = bid - 16;
        int l = t & 63, g = t >> 6;
        int colu0 = l & 15;
        int k0 = kk * 32 + (l >> 4) * 8;
#pragma unroll
        for (int i = 0; i < 4; ++i) {
            int nt = g * 4 + i;
            int colu = nt * 16 + colu0;
            ushort* dst = W1p + (((nt * 8) + kk) * 64 + l) * 8;
#pragma unroll
            for (int e = 0; e < 8; ++e) dst[e] = f2bf(W1[(k0 + e) * U + colu]);
        }
    }
}

// KB: per 32-row chunk (2048 blocks, 6 blocks/CU): staged-LDS bf16 MFMA scores,
// chunk softmax stats, unnormalized weights -> wout, bf16-LDS partial context.
__global__ __launch_bounds__(256, 6) void kb_scores(
    const float* __restrict__ values, const ushort* __restrict__ W1p,
    const float* __restrict__ pqb, const float* __restrict__ V,
    const float* __restrict__ bV, float* __restrict__ cstats,
    float* __restrict__ cpart, float* __restrict__ wout) {
    __shared__ ushort Alds[ROWS * 256];  // 16 KB, XOR-swizzled bf16 tile
    __shared__ float red[4][ROWS];
    __shared__ float wch[ROWS];
    const int bid = blockIdx.x;
    const int t = threadIdx.x;
    const int w = t >> 6, l = t & 63;
    char* lds = (char*)Alds;
    const int b = bid >> 7;              // 128 chunks per batch
    const int s0 = (bid & 127) * ROWS;

    // stage 32x256 fp32 -> bf16 LDS, byte ^= (row&7)<<4
    const float* src = values + ((size_t)(b * S + s0)) * D;
#pragma unroll
    for (int i = 0; i < 8; ++i) {
        int row = i * 4 + w;
        int col = l * 4;
        float4 v = *(const float4*)&src[row * 256 + col];
        ushort4 h;
        h.x = f2bf(v.x); h.y = f2bf(v.y); h.z = f2bf(v.z); h.w = f2bf(v.w);
        int byte = (row * 512 + col * 2) ^ ((row & 7) << 4);
        *(ushort4*)(lds + byte) = h;
    }
    __syncthreads();

    // MFMA scores
    const int lrow = l & 15, lk = l >> 4;
    f32x4 acc[2][4];
#pragma unroll
    for (int mt = 0; mt < 2; ++mt)
#pragma unroll
        for (int nt = 0; nt < 4; ++nt) acc[mt][nt] = (f32x4){0.f, 0.f, 0.f, 0.f};

    for (int kk = 0; kk < 8; ++kk) {
        short8 afr[2], bfr[4];
#pragma unroll
        for (int mt = 0; mt < 2; ++mt) {
            int row = mt * 16 + lrow;
            int byte = (row * 512 + kk * 64 + lk * 16) ^ ((row & 7) << 4);
            afr[mt] = *(const short8*)(lds + byte);
        }
#pragma unroll
        for (int nt = 0; nt < 4; ++nt)
            bfr[nt] = *(const short8*)&W1p[((((w * 4 + nt) * 8) + kk) * 64 + l) * 8];
#pragma unroll
        for (int mt = 0; mt < 2; ++mt)
#pragma unroll
            for (int nt = 0; nt < 4; ++nt)
                acc[mt][nt] = __builtin_amdgcn_mfma_f32_16x16x32_bf16(
                    afr[mt], bfr[nt], acc[mt][nt], 0, 0, 0);
    }

    // epilogue: tanh, .V, reduce over u
    float bb[4], vv[4];
#pragma unroll
    for (int nt = 0; nt < 4; ++nt) {
        int u = (w * 4 + nt) * 16 + lrow;
        bb[nt] = pqb[b * U + u];
        vv[nt] = V[u];
    }
#pragma unroll
    for (int mt = 0; mt < 2; ++mt) {
#pragma unroll
        for (int r = 0; r < 4; ++r) {
            float s = 0.f;
#pragma unroll
            for (int nt = 0; nt < 4; ++nt)
                s += fast_tanh(acc[mt][nt][r] + bb[nt]) * vv[nt];
            s += __shfl_xor(s, 1);
            s += __shfl_xor(s, 2);
            s += __shfl_xor(s, 4);
            s += __shfl_xor(s, 8);
            if (lrow == 0) red[w][mt * 16 + lk * 4 + r] = s;
        }
    }
    __syncthreads();

    if (t < ROWS) {  // lanes 0..31 of wave 0: chunk stats + unnormalized weights
        float s = red[0][t] + red[1][t] + red[2][t] + red[3][t] + bV[0];
        float m = s;
#pragma unroll
        for (int off = 16; off; off >>= 1) m = fmaxf(m, __shfl_xor(m, off));
        float z0 = __expf(s - m);
        wch[t] = z0;
        wout[b * S + s0 + t] = z0;  // KC rescales in place
        float z = z0;
#pragma unroll
        for (int off = 16; off; off >>= 1) z += __shfl_xor(z, off);
        if (t == 0) {
            cstats[2 * bid] = m;
            cstats[2 * bid + 1] = z;
        }
    }
    __syncthreads();

    // partial context from bf16 LDS: thread t owns column t (conflict-free u16 reads)
    union { uint i; float f; } cv;
    float cacc = 0.f;
#pragma unroll 8
    for (int r = 0; r < ROWS; ++r) {
        int byte = (r * 512 + t * 2) ^ ((r & 7) << 4);
        ushort u = *(const ushort*)(lds + byte);
        cv.i = (uint)u << 16;
        cacc = fmaf(wch[r], cv.f, cacc);
    }
    cpart[(size_t)bid * D + t] = cacc;
}

// KC: finisher, block = (batch b, quarter q), 128 chunks/batch.
__global__ void kc_final(const float* __restrict__ cstats, const float* __restrict__ cpart,
                         float* __restrict__ wout, float* __restrict__ ctx) {
    __shared__ float scl[NCHK];
    __shared__ float stats2[2];
    __shared__ float part[4][64];
    int b = blockIdx.x >> 2, q = blockIdx.x & 3;
    int t = threadIdx.x;

    if (t < 64) {  // reduce 128 chunk stats with 64 lanes (2 chunks each)
        float m1 = cstats[2 * (b * NCHK + t)];
        float z1 = cstats[2 * (b * NCHK + t) + 1];
        float m2 = cstats[2 * (b * NCHK + 64 + t)];
        float z2 = cstats[2 * (b * NCHK + 64 + t) + 1];
        float M = fmaxf(m1, m2);
#pragma unroll
        for (int off = 32; off; off >>= 1) M = fmaxf(M, __shfl_xor(M, off));
        float zz = z1 * __expf(m1 - M) + z2 * __expf(m2 - M);
#pragma unroll
        for (int off = 32; off; off >>= 1) zz += __shfl_xor(zz, off);
        if (t == 0) { stats2[0] = M; stats2[1] = zz; }
    }
    __syncthreads();
    float M = stats2[0];
    float invZ = 1.0f / stats2[1];
    if (t < NCHK) scl[t] = __expf(cstats[2 * (b * NCHK + t)] - M);
    __syncthreads();

    int tq = t >> 6, dl = t & 63;
    int d = q * 64 + dl;
    float acc = 0.f;
#pragma unroll
    for (int i = 0; i < 32; ++i) {
        int c = tq * 32 + i;
        acc = fmaf(scl[c], cpart[(size_t)(b * NCHK + c) * D + d], acc);
    }
    part[tq][dl] = acc;

#pragma unroll
    for (int i = 0; i < 4; ++i) {
        int ss = q * 1024 + i * 256 + t;
        wout[b * S + ss] *= scl[ss >> 5] * invZ;  // 32 rows per chunk
    }
    __syncthreads();
    if (t < 64)
        ctx[b * D + q * 64 + t] =
            (part[0][t] + part[1][t] + part[2][t] + part[3][t]) * invZ;
}

extern "C" void kernel_launch(void* const* d_in, const int* in_sizes, int n_in,
                              void* d_out, int out_size, void* d_ws, size_t ws_size,
                              hipStream_t stream) {
    const float* values = (const float*)d_in[0];
    const float* query  = (const float*)d_in[1];
    const float* W1     = (const float*)d_in[2];
    const float* b1     = (const float*)d_in[3];
    const float* W2     = (const float*)d_in[4];
    const float* b2     = (const float*)d_in[5];
    const float* V      = (const float*)d_in[6];
    const float* bV     = (const float*)d_in[7];

    float* out  = (float*)d_out;
    float* ctx  = out;          // [B, D]
    float* wout = out + B * D;  // [B, S, 1]

    float* ws     = (float*)d_ws;
    float* pqb    = ws;                    // 4096
    float* cstats = pqb + B * U;           // 2*B*NCHK = 4096
    float* cpart  = cstats + 2 * B * NCHK; // B*NCHK*D = 524288
    ushort* W1p   = (ushort*)(cpart + (size_t)B * NCHK * D);  // 65536 ushorts

    ka_setup<<<24, 256, 0, stream>>>(query, W2, b2, b1, W1, pqb, W1p);
    kb_scores<<<B * NCHK, 256, 0, stream>>>(values, W1p, pqb, V, bV,
                                            cstats, cpart, wout);
    kc_final<<<B * 4, 256, 0, stream>>>(cstats, cpart, wout, ctx);
}